// Round 5
// baseline (11814.471 us; speedup 1.0000x reference)
//
#include <hip/hip_runtime.h>
#include <math.h>

#define T_LEN 512
#define AGT __HIP_MEMORY_SCOPE_AGENT

// ---------------- workspace layout (bytes) ----------------
// 0x0000 : unsigned barA            (memset 0 each launch)
// 0x0200 : unsigned barB            (separate cache line)
// 0x0400 : float null_g[2][8]       (parity-buffered null_attn)
// 0x0600 : float kcg[2][5][2][32]   (par, mech, variant, DC)
// 0x1000 : float vcg[2][5][2][128]
// 0x4000 : float keys[512*6*64]
// 0x4000+0xC0000 : float vals[512*6*64]
// 0x4000+2*0xC0000 : float hidden[512*640]

__device__ __forceinline__ float tanh_f(float x) {
    const float e = __expf(2.f * x);
    return 1.f - 2.f / (e + 1.f);
}

// ============ kernel 1: key/value projections (parallel) ============
__global__ __launch_bounds__(128) void precompute_kv(
    const float* __restrict__ bert, const int* __restrict__ uidx, const int* __restrict__ pidx,
    const float* __restrict__ disg, const float* __restrict__ udisg,
    const float* __restrict__ utab, const float* __restrict__ ptab,
    const float* __restrict__ Wk0, const float* __restrict__ Wv0,
    const float* __restrict__ Wk1, const float* __restrict__ Wv1,
    const float* __restrict__ Wk2, const float* __restrict__ Wv2,
    const float* __restrict__ Wk3, const float* __restrict__ Wv3,
    const float* __restrict__ Wk4, const float* __restrict__ Wv4,
    float* __restrict__ keys, float* __restrict__ vals)
{
    __shared__ float x[768 + 50 + 20 + 2 + 2];
    const int t = blockIdx.x, tid = threadIdx.x;
    for (int i = tid; i < 768; i += 128) x[i] = bert[t * 768 + i];
    const int u = uidx[t], p = pidx[t];
    for (int i = tid; i < 50; i += 128) x[768 + i] = utab[u * 50 + i];
    for (int i = tid; i < 20; i += 128) x[818 + i] = ptab[p * 20 + i];
    if (tid < 2) x[838 + tid] = disg[t * 2 + tid];
    if (tid >= 2 && tid < 4) x[840 + (tid - 2)] = udisg[t * 2 + (tid - 2)];
    __syncthreads();
    const int j = tid & 63, isv = tid >> 6;
    float* outb = (isv ? vals : keys) + t * 384;
    {   const float* W = isv ? Wv0 : Wk0; float a = 0.f;
        for (int i = 0; i < 768; ++i) a += x[i] * W[i * 64 + j];
        outb[0 * 64 + j] = a; }
    {   const float* W = isv ? Wv1 : Wk1; float a = 0.f;
        for (int i = 0; i < 50; ++i) a += x[768 + i] * W[i * 64 + j];
        outb[1 * 64 + j] = a; }
    {   const float* W = isv ? Wv2 : Wk2; float a = 0.f;
        for (int i = 0; i < 20; ++i) a += x[818 + i] * W[i * 64 + j];
        outb[2 * 64 + j] = a; }
    {   const float* W = isv ? Wv3 : Wk3;
        outb[3 * 64 + j] = x[838] * W[j] + x[839] * W[64 + j]; }
    {   const float* W = isv ? Wv4 : Wk4;
        outb[4 * 64 + j] = x[840] * W[j] + x[841] * W[64 + j]; }
    outb[5 * 64 + j] = 0.f;   // null key/value row
}

// ============ kernel 2: the sequential RIM scan ============
// Grid = 33; only blockIdx.x%8==0 work (mech = bx>>3) -> XCD co-location.
// 512 threads / 8 waves. 6-stage pipeline, 6 syncthreads/step:
//  X1: w0-3 q-partials | w4 qc0 | w5 kc0+pub | w6-7 vc0+pub
//  X2: w7 attn+softmax+inp+null+arriveA | w0-6 reg-resident Whh.h partial | w0 kv prefetch
//  Y : pollA hidden (w0 lane0) ; gate-finish + LSTM -> shn
//  Z : mask; variant-1 matvecs ONLY if active; leader-elected arriveB
//      (per-wave vmcnt drain + LDS counter); w0 lane0 polls B (overlapped)
//  W : ctx logits (w3-7, remote kc) ; remote vc loads (tid<128)
//  V : ctx softmax + h2 + state/hidden store

#define SMEM_FLOATS 35408

__global__ void __attribute__((amdgpu_flat_work_group_size(512, 512), amdgpu_waves_per_eu(2, 2)))
rim_scan(
    const float* __restrict__ Wq, const float* __restrict__ Wih, const float* __restrict__ Whh,
    const float* __restrict__ b_lstm, const float* __restrict__ Wqc, const float* __restrict__ Wkc,
    const float* __restrict__ Wvc,
    const float* __restrict__ keys, const float* __restrict__ vals,
    float* __restrict__ hidden,
    unsigned* __restrict__ barA, unsigned* __restrict__ barB, float* __restrict__ null_g,
    float* __restrict__ kcg, float* __restrict__ vcg)
{
    if (blockIdx.x & 7) return;                 // XCD-pinning dummies
    const int mech = blockIdx.x >> 3;

    extern __shared__ float sm[];
    float* swq  = sm;            // 8192  Wq_T  [64 out][128 K] swizzled
    float* swqc = sm + 8192;     // 4096  Wqc_T [32][128]
    float* swkc = sm + 12288;    // 4096  Wkc_T [32][128]
    float* swvc = sm + 16384;    // 16384 Wvc_T [128][128]
    float* skey = sm + 32768;    // 2*384 key double-buffer
    float* sval = sm + 33536;    // 2*384 val double-buffer
    float* sqp  = sm + 34304;    // 256   q partials (4 segs x 64)
    float* sh   = sm + 34560;    // 128   h state
    float* shn  = sm + 34688;    // 128   h_new candidate
    float* sop  = sm + 34816;    // 192   gate operand: [inp(64) | h(128)]
    float* qcl  = sm + 35008;    // 64    qc[var][32]
    float* kcl  = sm + 35072;    // 64    kc[var][32]
    float* vcl  = sm + 35136;    // 256   vc[var][128]
    float* slog = sm + 35392;    // 8     ctx logits
    float* snull= sm + 35400;    // 8
    __shared__ unsigned sbar;    // Z-stage arrival counter

    const int tid = threadIdx.x;
    const int lane = tid & 63, wv = tid >> 6;

    // ---- stage transposed+swizzled weights into LDS
    for (int idx = tid; idx < 8192; idx += 512) {
        const int i = idx >> 6, j = idx & 63;
        swq[j * 128 + ((((i >> 2) ^ (j & 7)) << 2) | (i & 3))] = Wq[mech * 8192 + idx];
    }
    for (int idx = tid; idx < 4096; idx += 512) {
        const int i = idx >> 5, c = idx & 31;
        const int pos = c * 128 + ((((i >> 2) ^ (c & 7)) << 2) | (i & 3));
        swqc[pos] = Wqc[mech * 4096 + idx];
        swkc[pos] = Wkc[mech * 4096 + idx];
    }
    for (int idx = tid; idx < 16384; idx += 512) {
        const int i = idx >> 7, o = idx & 127;
        swvc[o * 128 + ((((i >> 2) ^ (o & 7)) << 2) | (i & 3))] = Wvc[mech * 16384 + idx];
    }
    if (tid < 384) { skey[tid] = keys[tid]; sval[tid] = vals[tid]; }  // prime t=0
    if (tid < 192) sop[tid] = 0.f;
    if (tid < 128) { sh[tid] = 0.f; shn[tid] = 0.f; }
    if (tid == 0) sbar = 0;

    // ---- gate weights in registers. quad j covers cell j's 4 gates:
    // pair even -> (i_j, g_j), pair odd -> (f_j, o_j); s = K-half.
    const int pair = tid >> 1, s = tid & 1;
    const int o0 = (pair >> 1) + (pair & 1) * 128;   // i_j or f_j
    const int o1 = o0 + 256;                          // g_j or o_j
    float wA[96], wB[96];
    if (s == 0) {
        #pragma unroll
        for (int k = 0; k < 64; ++k) {
            wA[k] = Wih[mech * 32768 + k * 512 + o0];
            wB[k] = Wih[mech * 32768 + k * 512 + o1];
        }
        #pragma unroll
        for (int k = 0; k < 32; ++k) {
            wA[64 + k] = Whh[mech * 65536 + k * 512 + o0];
            wB[64 + k] = Whh[mech * 65536 + k * 512 + o1];
        }
    } else {
        #pragma unroll
        for (int k = 0; k < 96; ++k) {
            wA[k] = Whh[mech * 65536 + (32 + k) * 512 + o0];
            wB[k] = Whh[mech * 65536 + (32 + k) * 512 + o1];
        }
    }
    const float b0v = (s == 0) ? b_lstm[mech * 512 + o0] : 0.f;
    const float b1v = (s == 0) ? b_lstm[mech * 512 + o1] : 0.f;
    float c_reg = 0.f, cn = 0.f;
    __syncthreads();

    #pragma unroll 1
    for (int t = 0; t < T_LEN; ++t) {
        const int par = t & 1;
        const float* kb = skey + par * 384;
        const float* vb = sval + par * 384;

        // one-wave qc/kc matvec (2 lanes/out over 32 outs)
        auto qk32 = [&](const float* W, const float* hsrc, int var, float* dstL, bool pub) {
            const int out = lane >> 1, s2 = lane & 1, rx = out & 7;
            const float* wrow = W + out * 128;
            const float4* h4 = (const float4*)(hsrc + s2 * 64);
            float p = 0.f;
            #pragma unroll
            for (int j = 0; j < 16; ++j) {
                const float4 w = *(const float4*)(wrow + (((s2 * 16 + j) ^ rx) << 2));
                const float4 hv = h4[j];
                p += w.x * hv.x + w.y * hv.y + w.z * hv.z + w.w * hv.w;
            }
            p += __shfl_xor(p, 1);
            if (s2 == 0) {
                dstL[var * 32 + out] = p;
                if (pub)
                    __hip_atomic_store(&kcg[((par * 5 + mech) * 2 + var) * 32 + out],
                                       p, __ATOMIC_RELAXED, AGT);
            }
        };
        // two-wave vc matvec (1 lane/out over 128 outs, full K)
        auto vc128 = [&](const float* hsrc, int var) {
            const int out = (wv - 6) * 64 + lane, rx = out & 7;
            const float* wrow = swvc + out * 128;
            const float4* h4 = (const float4*)hsrc;
            float p = 0.f;
            #pragma unroll
            for (int c = 0; c < 32; ++c) {
                const float4 w = *(const float4*)(wrow + ((c ^ rx) << 2));
                const float4 hv = h4[c];
                p += w.x * hv.x + w.y * hv.y + w.z * hv.z + w.w * hv.w;
            }
            vcl[var * 128 + out] = p;
            __hip_atomic_store(&vcg[((par * 5 + mech) * 2 + var) * 128 + out],
                               p, __ATOMIC_RELAXED, AGT);
        };

        // ================= X1 =================
        if (wv < 4) {
            // q partials: out=lane, K-seg = wv*32
            const int out = lane, rx = out & 7;
            const float* wrow = swq + out * 128;
            const float4* h4 = (const float4*)(sh + wv * 32);
            float acc = 0.f;
            #pragma unroll
            for (int j = 0; j < 8; ++j) {
                const float4 w = *(const float4*)(wrow + (((wv * 8 + j) ^ rx) << 2));
                const float4 hv = h4[j];
                acc += w.x * hv.x + w.y * hv.y + w.z * hv.z + w.w * hv.w;
            }
            sqp[wv * 64 + out] = acc;
        } else if (wv == 4) {
            qk32(swqc, sh, 0, qcl, false);
        } else if (wv == 5) {
            qk32(swkc, sh, 0, kcl, true);
        } else {
            vc128(sh, 0);
        }
        __syncthreads();   // SYNC1

        // ================= X2 =================
        float hA = b0v, hB = b1v;
        if (wv == 7) {
            // attn: q-sum, 6 logits, softmax, inp, null publish, arrive A
            const float q = sqp[lane] + sqp[64 + lane] + sqp[128 + lane] + sqp[192 + lane];
            float l[6];
            #pragma unroll
            for (int k = 0; k < 6; ++k) {
                float p = q * kb[k * 64 + lane];
                p += __shfl_down(p, 32); p += __shfl_down(p, 16); p += __shfl_down(p, 8);
                p += __shfl_down(p, 4);  p += __shfl_down(p, 2);  p += __shfl_down(p, 1);
                l[k] = __shfl(p, 0) * 0.125f;
            }
            const float mx = fmaxf(fmaxf(fmaxf(l[0], l[1]), fmaxf(l[2], l[3])), fmaxf(l[4], l[5]));
            const float e0 = __expf(l[0] - mx), e1 = __expf(l[1] - mx), e2 = __expf(l[2] - mx);
            const float e3 = __expf(l[3] - mx), e4 = __expf(l[4] - mx), e5 = __expf(l[5] - mx);
            const float inv = 1.f / (e0 + e1 + e2 + e3 + e4 + e5);
            sop[lane] = (e0 * vb[lane] + e1 * vb[64 + lane] + e2 * vb[128 + lane]
                       + e3 * vb[192 + lane] + e4 * vb[256 + lane] + e5 * vb[320 + lane]) * inv;
            if (lane == 0) {
                __hip_atomic_store(&null_g[par * 8 + mech], e5 * inv, __ATOMIC_RELAXED, AGT);
                asm volatile("s_waitcnt vmcnt(0)" ::: "memory");
                __hip_atomic_fetch_add(barA, 1u, __ATOMIC_RELAXED, AGT);
            }
        } else {
            // Whh.h partial of gates (weights in regs)
            if (s == 0) {
                const float4* hb = (const float4*)(sop + 64);
                #pragma unroll
                for (int k = 0; k < 8; ++k) {
                    const float4 v = hb[k];
                    hA += v.x * wA[64 + 4*k] + v.y * wA[64 + 4*k + 1] + v.z * wA[64 + 4*k + 2] + v.w * wA[64 + 4*k + 3];
                    hB += v.x * wB[64 + 4*k] + v.y * wB[64 + 4*k + 1] + v.z * wB[64 + 4*k + 2] + v.w * wB[64 + 4*k + 3];
                }
            } else {
                const float4* hb = (const float4*)(sop + 96);
                #pragma unroll
                for (int q = 0; q < 24; ++q) {
                    const float4 v = hb[q];
                    hA += v.x * wA[4*q] + v.y * wA[4*q + 1] + v.z * wA[4*q + 2] + v.w * wA[4*q + 3];
                    hB += v.x * wB[4*q] + v.y * wB[4*q + 1] + v.z * wB[4*q + 2] + v.w * wB[4*q + 3];
                }
            }
            if (wv == 0) {
                // kv prefetch for t+1
                const int tn = (t < T_LEN - 1) ? t + 1 : t;
                const int nx = (t + 1) & 1;
                const float4* kn = (const float4*)(keys + tn * 384);
                const float4* vn = (const float4*)(vals + tn * 384);
                float4* kd = (float4*)(skey + nx * 384);
                float4* vd = (float4*)(sval + nx * 384);
                #pragma unroll
                for (int rep = 0; rep < 3; ++rep) {
                    const int i = rep * 64 + lane;
                    if (i < 96) kd[i] = kn[i];
                    else if (i < 192) vd[i - 96] = vn[i - 96];
                }
            }
        }
        __syncthreads();   // SYNC2

        // ================= Y =================
        if (tid == 0) {   // poll A (hidden behind gates), fetch nulls
            const unsigned tgt = 5u * (unsigned)(t + 1);
            while (__hip_atomic_load(barA, __ATOMIC_RELAXED, AGT) < tgt)
                __builtin_amdgcn_s_sleep(1);
            asm volatile("" ::: "memory");
            #pragma unroll
            for (int mm = 0; mm < 5; ++mm)
                snull[mm] = __hip_atomic_load(&null_g[par * 8 + mm], __ATOMIC_RELAXED, AGT);
        }
        {
            float p0 = hA, p1 = hB;
            if (wv == 7) {
                const float4* op = (const float4*)(sop + s * 96);
                #pragma unroll
                for (int q = 0; q < 24; ++q) {
                    const float4 v = op[q];
                    p0 += v.x * wA[4*q] + v.y * wA[4*q + 1] + v.z * wA[4*q + 2] + v.w * wA[4*q + 3];
                    p1 += v.x * wB[4*q] + v.y * wB[4*q + 1] + v.z * wB[4*q + 2] + v.w * wB[4*q + 3];
                }
            } else if (s == 0) {
                const float4* op = (const float4*)sop;
                #pragma unroll
                for (int q = 0; q < 16; ++q) {
                    const float4 v = op[q];
                    p0 += v.x * wA[4*q] + v.y * wA[4*q + 1] + v.z * wA[4*q + 2] + v.w * wA[4*q + 3];
                    p1 += v.x * wB[4*q] + v.y * wB[4*q + 1] + v.z * wB[4*q + 2] + v.w * wB[4*q + 3];
                }
            }
            const float r0 = p0 + __shfl_xor(p0, 1);
            const float r1 = p1 + __shfl_xor(p1, 1);
            const float t0 = __shfl_xor(r0, 2);
            const float t1 = __shfl_xor(r1, 2);
            const bool even = ((pair & 1) == 0);
            const float gi = even ? r0 : t0;
            const float gg = even ? r1 : t1;
            const float gf = even ? t0 : r0;
            const float go = even ? t1 : r1;
            const float si = 1.f / (1.f + __expf(-gi));
            const float sf = 1.f / (1.f + __expf(-gf));
            const float so = 1.f / (1.f + __expf(-go));
            cn = sf * c_reg + si * tanh_f(gg);
            const float hn = so * tanh_f(cn);
            if ((tid & 3) == 0) shn[tid >> 2] = hn;
        }
        __syncthreads();   // SYNC3

        // ================= Z =================
        int selfAct;
        {
            const float myn = snull[mech]; int r = 0;
            #pragma unroll
            for (int mm = 0; mm < 5; ++mm) {
                const float o = snull[mm];
                r += (o < myn || (o == myn && mm < mech)) ? 1 : 0;
            }
            selfAct = (r < 3) ? 1 : 0;
        }
        c_reg = selfAct ? cn : c_reg;
        if (selfAct) {
            if (wv == 4)      qk32(swqc, shn, 1, qcl, false);
            else if (wv == 5) qk32(swkc, shn, 1, kcl, true);
            else if (wv >= 6) vc128(shn, 1);
        }
        if ((wv >= 5) && lane == 0) {   // waves 5,6,7: drain + elect leader for arrive B
            asm volatile("s_waitcnt vmcnt(0)" ::: "memory");
            const unsigned old = atomicAdd(&sbar, 1u);
            if (old == 2u)
                __hip_atomic_fetch_add(barB, 1u, __ATOMIC_RELAXED, AGT);
        }
        if (tid == 0) {   // poll B (overlapped with local Z work of waves 4-7)
            const unsigned tgt = 5u * (unsigned)(t + 1);
            while (__hip_atomic_load(barB, __ATOMIC_RELAXED, AGT) < tgt)
                __builtin_amdgcn_s_sleep(1);
            asm volatile("" ::: "memory");
        }
        __syncthreads();   // SYNC4

        // ================= W =================
        float v0 = 0.f, v1 = 0.f, v2 = 0.f, v3 = 0.f, v4 = 0.f;
        if (wv >= 3 && lane < 32) {
            const int m2 = wv - 3;
            const float nm = snull[m2]; int r2 = 0;
            #pragma unroll
            for (int mm = 0; mm < 5; ++mm) {
                const float o = snull[mm];
                r2 += (o < nm || (o == nm && mm < m2)) ? 1 : 0;
            }
            const int sel2 = (r2 < 3) ? 1 : 0;
            const float kcv = (m2 == mech) ? kcl[sel2 * 32 + lane]
                : __hip_atomic_load(&kcg[((par * 5 + m2) * 2 + sel2) * 32 + lane], __ATOMIC_RELAXED, AGT);
            float p = qcl[selfAct * 32 + lane] * kcv;
            p += __shfl_down(p, 16); p += __shfl_down(p, 8); p += __shfl_down(p, 4);
            p += __shfl_down(p, 2);  p += __shfl_down(p, 1);
            if (lane == 0) slog[m2] = p * 0.17677669529663687f;
        }
        if (tid < 128) {
            int sel[5];
            #pragma unroll
            for (int mm = 0; mm < 5; ++mm) {
                const float nm = snull[mm]; int rr = 0;
                #pragma unroll
                for (int m3 = 0; m3 < 5; ++m3) {
                    const float o = snull[m3];
                    rr += (o < nm || (o == nm && m3 < mm)) ? 1 : 0;
                }
                sel[mm] = (rr < 3) ? 1 : 0;
            }
            v0 = (mech == 0) ? vcl[sel[0] * 128 + tid]
               : __hip_atomic_load(&vcg[((par * 5 + 0) * 2 + sel[0]) * 128 + tid], __ATOMIC_RELAXED, AGT);
            v1 = (mech == 1) ? vcl[sel[1] * 128 + tid]
               : __hip_atomic_load(&vcg[((par * 5 + 1) * 2 + sel[1]) * 128 + tid], __ATOMIC_RELAXED, AGT);
            v2 = (mech == 2) ? vcl[sel[2] * 128 + tid]
               : __hip_atomic_load(&vcg[((par * 5 + 2) * 2 + sel[2]) * 128 + tid], __ATOMIC_RELAXED, AGT);
            v3 = (mech == 3) ? vcl[sel[3] * 128 + tid]
               : __hip_atomic_load(&vcg[((par * 5 + 3) * 2 + sel[3]) * 128 + tid], __ATOMIC_RELAXED, AGT);
            v4 = (mech == 4) ? vcl[sel[4] * 128 + tid]
               : __hip_atomic_load(&vcg[((par * 5 + 4) * 2 + sel[4]) * 128 + tid], __ATOMIC_RELAXED, AGT);
        }
        __syncthreads();   // SYNC5

        // ================= V =================
        if (tid < 128) {
            const float l0 = slog[0], l1 = slog[1], l2 = slog[2], l3 = slog[3], l4 = slog[4];
            const float mx = fmaxf(fmaxf(fmaxf(l0, l1), fmaxf(l2, l3)), l4);
            const float e0 = __expf(l0 - mx), e1 = __expf(l1 - mx), e2 = __expf(l2 - mx);
            const float e3 = __expf(l3 - mx), e4 = __expf(l4 - mx);
            const float inv = 1.f / (e0 + e1 + e2 + e3 + e4);
            float hv = selfAct ? shn[tid] : sh[tid];
            if (selfAct) hv += (e0 * v0 + e1 * v1 + e2 * v2 + e3 * v3 + e4 * v4) * inv;
            sh[tid] = hv;
            sop[64 + tid] = hv;
            hidden[t * 640 + mech * 128 + tid] = hv;
        }
        if (tid == 0) sbar = 0;
        __syncthreads();   // SYNC6
    }
}

// ============ kernel 3: classifier ============
__global__ __launch_bounds__(256) void cls_kernel(
    const float* __restrict__ hidden, const float* __restrict__ Wcls,
    const float* __restrict__ bcls, float* __restrict__ out)
{
    const int t = blockIdx.x * 256 + threadIdx.x;
    if (t >= T_LEN) return;
    float a0 = bcls[0], a1 = bcls[1];
    for (int d = 0; d < 640; ++d) {
        const float h = hidden[t * 640 + d];
        a0 += h * Wcls[d * 2 + 0];
        a1 += h * Wcls[d * 2 + 1];
    }
    out[t * 2 + 0] = a0;
    out[t * 2 + 1] = a1;
}

extern "C" void kernel_launch(void* const* d_in, const int* in_sizes, int n_in,
                              void* d_out, int out_size, void* d_ws, size_t ws_size,
                              hipStream_t stream)
{
    (void)in_sizes; (void)n_in; (void)out_size; (void)ws_size;
    const float* bert  = (const float*)d_in[0];
    const int*   uidx  = (const int*)d_in[1];
    const int*   pidx  = (const int*)d_in[2];
    const float* disg  = (const float*)d_in[3];
    const float* udisg = (const float*)d_in[4];
    const float* utab  = (const float*)d_in[5];
    const float* ptab  = (const float*)d_in[6];
    const float* Wk0 = (const float*)d_in[7],  *Wv0 = (const float*)d_in[8];
    const float* Wk1 = (const float*)d_in[9],  *Wv1 = (const float*)d_in[10];
    const float* Wk2 = (const float*)d_in[11], *Wv2 = (const float*)d_in[12];
    const float* Wk3 = (const float*)d_in[13], *Wv3 = (const float*)d_in[14];
    const float* Wk4 = (const float*)d_in[15], *Wv4 = (const float*)d_in[16];
    const float* Wq   = (const float*)d_in[17];
    const float* Wih  = (const float*)d_in[18];
    const float* Whh  = (const float*)d_in[19];
    const float* bl   = (const float*)d_in[20];
    const float* Wqc  = (const float*)d_in[21];
    const float* Wkc  = (const float*)d_in[22];
    const float* Wvc  = (const float*)d_in[23];
    const float* Wcls = (const float*)d_in[24];
    const float* bcls = (const float*)d_in[25];

    char* ws = (char*)d_ws;
    unsigned* barA = (unsigned*)ws;
    unsigned* barB = (unsigned*)(ws + 0x200);
    float* null_g  = (float*)(ws + 0x400);
    float* kcg     = (float*)(ws + 0x600);
    float* vcg     = (float*)(ws + 0x1000);
    float* keys    = (float*)(ws + 0x4000);
    float* vals    = (float*)(ws + 0x4000 + 786432);
    float* hidden  = (float*)(ws + 0x4000 + 2 * 786432);

    hipMemsetAsync(d_ws, 0, 0x400, stream);   // zero both barrier counters

    hipLaunchKernelGGL(precompute_kv, dim3(T_LEN), dim3(128), 0, stream,
        bert, uidx, pidx, disg, udisg, utab, ptab,
        Wk0, Wv0, Wk1, Wv1, Wk2, Wv2, Wk3, Wv3, Wk4, Wv4, keys, vals);

    const int smem_bytes = SMEM_FLOATS * 4;   // 141632 B < 160 KiB
    (void)hipFuncSetAttribute((const void*)rim_scan,
                              hipFuncAttributeMaxDynamicSharedMemorySize, smem_bytes);
    hipLaunchKernelGGL(rim_scan, dim3(33), dim3(512), smem_bytes, stream,
        Wq, Wih, Whh, bl, Wqc, Wkc, Wvc, keys, vals, hidden, barA, barB, null_g, kcg, vcg);

    hipLaunchKernelGGL(cls_kernel, dim3(2), dim3(256), 0, stream,
        hidden, Wcls, bcls, (float*)d_out);
}

// Round 6
// 5032.248 us; speedup vs baseline: 2.3478x; 2.3478x over previous
//
#include <hip/hip_runtime.h>
#include <math.h>

#define T_LEN 512
#define AGT __HIP_MEMORY_SCOPE_AGENT

// ---------------- workspace layout (bytes) ----------------
// 0x0100 + m*0x100 : unsigned flag[m], m=0..4 (tag = t+1; memset 0 each launch)
// 0x0600 : float null_g[2][8]        (parity-buffered null_attn)
// 0x0700 : float kcg[2][5][2][32]    (par, mech, variant, DC)   2560 B
// 0x1200 : float vcg[2][5][2][128]   10240 B
// 0x4000 : float keys[512*6*64]
// 0x4000+0xC0000 : float vals[512*6*64]
// 0x4000+2*0xC0000 : float hidden[512*640]

__device__ __forceinline__ float tanh_f(float x) {
    const float e = __expf(2.f * x);
    return 1.f - 2.f / (e + 1.f);
}

// ============ kernel 1: key/value projections (parallel) ============
__global__ __launch_bounds__(128) void precompute_kv(
    const float* __restrict__ bert, const int* __restrict__ uidx, const int* __restrict__ pidx,
    const float* __restrict__ disg, const float* __restrict__ udisg,
    const float* __restrict__ utab, const float* __restrict__ ptab,
    const float* __restrict__ Wk0, const float* __restrict__ Wv0,
    const float* __restrict__ Wk1, const float* __restrict__ Wv1,
    const float* __restrict__ Wk2, const float* __restrict__ Wv2,
    const float* __restrict__ Wk3, const float* __restrict__ Wv3,
    const float* __restrict__ Wk4, const float* __restrict__ Wv4,
    float* __restrict__ keys, float* __restrict__ vals)
{
    __shared__ float x[768 + 50 + 20 + 2 + 2];
    const int t = blockIdx.x, tid = threadIdx.x;
    for (int i = tid; i < 768; i += 128) x[i] = bert[t * 768 + i];
    const int u = uidx[t], p = pidx[t];
    for (int i = tid; i < 50; i += 128) x[768 + i] = utab[u * 50 + i];
    for (int i = tid; i < 20; i += 128) x[818 + i] = ptab[p * 20 + i];
    if (tid < 2) x[838 + tid] = disg[t * 2 + tid];
    if (tid >= 2 && tid < 4) x[840 + (tid - 2)] = udisg[t * 2 + (tid - 2)];
    __syncthreads();
    const int j = tid & 63, isv = tid >> 6;
    float* outb = (isv ? vals : keys) + t * 384;
    {   const float* W = isv ? Wv0 : Wk0; float a = 0.f;
        for (int i = 0; i < 768; ++i) a += x[i] * W[i * 64 + j];
        outb[0 * 64 + j] = a; }
    {   const float* W = isv ? Wv1 : Wk1; float a = 0.f;
        for (int i = 0; i < 50; ++i) a += x[768 + i] * W[i * 64 + j];
        outb[1 * 64 + j] = a; }
    {   const float* W = isv ? Wv2 : Wk2; float a = 0.f;
        for (int i = 0; i < 20; ++i) a += x[818 + i] * W[i * 64 + j];
        outb[2 * 64 + j] = a; }
    {   const float* W = isv ? Wv3 : Wk3;
        outb[3 * 64 + j] = x[838] * W[j] + x[839] * W[64 + j]; }
    {   const float* W = isv ? Wv4 : Wk4;
        outb[4 * 64 + j] = x[840] * W[j] + x[841] * W[64 + j]; }
    outb[5 * 64 + j] = 0.f;   // null key/value row
}

// ============ kernel 2: the sequential RIM scan ============
// Grid = 33; only blockIdx.x%8==0 work (mech = bx>>3) -> XCD co-location.
// 512 threads / 8 waves. R4 schedule (ONE rendezvous/step) with R5's
// conflict-free matvec shapes and a parallel tagged-flag rendezvous:
//  S0: w0-3 q-partials | w4 qc0 | w5 kc0+pub | w6-7 vc0+pub
//  S1: w0 attn+softmax+inp+null | w1-2 kv prefetch
//  S2: gates (reg weights) + LSTM via quad shuffles -> shn
//  S3: w1 qc1 | w2 kc1+pub | w3-4 vc1+pub
//  SYNC (drains all waves' vmem) -> FLAG: tid0 stores tag t+1; lanes 0-4
//  poll the 4 remote flags in PARALLEL (monotone tags; skew<=1, parity-safe)
//  and fetch remote nulls.
//  S5: ctx logits (w3-7) + remote vc loads (tid<128)
//  S6: ctx softmax + h2 + state/hidden store

#define SMEM_FLOATS 35408

__global__ void __attribute__((amdgpu_flat_work_group_size(512, 512), amdgpu_waves_per_eu(2, 2)))
rim_scan(
    const float* __restrict__ Wq, const float* __restrict__ Wih, const float* __restrict__ Whh,
    const float* __restrict__ b_lstm, const float* __restrict__ Wqc, const float* __restrict__ Wkc,
    const float* __restrict__ Wvc,
    const float* __restrict__ keys, const float* __restrict__ vals,
    float* __restrict__ hidden,
    unsigned* __restrict__ flags, float* __restrict__ null_g,
    float* __restrict__ kcg, float* __restrict__ vcg)
{
    if (blockIdx.x & 7) return;                 // XCD-pinning dummies
    const int mech = blockIdx.x >> 3;

    extern __shared__ float sm[];
    float* swq  = sm;            // 8192  Wq_T  [64 out][128 K] swizzled
    float* swqc = sm + 8192;     // 4096  Wqc_T [32][128]
    float* swkc = sm + 12288;    // 4096  Wkc_T [32][128]
    float* swvc = sm + 16384;    // 16384 Wvc_T [128][128]
    float* skey = sm + 32768;    // 2*384 key double-buffer
    float* sval = sm + 33536;    // 2*384 val double-buffer
    float* sqp  = sm + 34304;    // 256   q partials (4 segs x 64)
    float* sh   = sm + 34560;    // 128   h state
    float* shn  = sm + 34688;    // 128   h_new candidate
    float* sop  = sm + 34816;    // 192   gate operand: [inp(64) | h(128)]
    float* qcl  = sm + 35008;    // 64    qc[var][32]
    float* kcl  = sm + 35072;    // 64    kc[var][32]
    float* vcl  = sm + 35136;    // 256   vc[var][128]
    float* slog = sm + 35392;    // 8     ctx logits
    float* snull= sm + 35400;    // 8

    const int tid = threadIdx.x;
    const int lane = tid & 63, wv = tid >> 6;

    // ---- stage transposed+swizzled weights into LDS
    for (int idx = tid; idx < 8192; idx += 512) {
        const int i = idx >> 6, j = idx & 63;
        swq[j * 128 + ((((i >> 2) ^ (j & 7)) << 2) | (i & 3))] = Wq[mech * 8192 + idx];
    }
    for (int idx = tid; idx < 4096; idx += 512) {
        const int i = idx >> 5, c = idx & 31;
        const int pos = c * 128 + ((((i >> 2) ^ (c & 7)) << 2) | (i & 3));
        swqc[pos] = Wqc[mech * 4096 + idx];
        swkc[pos] = Wkc[mech * 4096 + idx];
    }
    for (int idx = tid; idx < 16384; idx += 512) {
        const int i = idx >> 7, o = idx & 127;
        swvc[o * 128 + ((((i >> 2) ^ (o & 7)) << 2) | (i & 3))] = Wvc[mech * 16384 + idx];
    }
    if (tid < 384) { skey[tid] = keys[tid]; sval[tid] = vals[tid]; }  // prime t=0
    if (tid < 192) sop[tid] = 0.f;
    if (tid < 128) { sh[tid] = 0.f; shn[tid] = 0.f; }

    // ---- gate weights in registers. quad j covers cell j's 4 gates:
    // pair even -> (i_j, g_j), pair odd -> (f_j, o_j); s = K-half.
    const int pair = tid >> 1, s = tid & 1;
    const int o0 = (pair >> 1) + (pair & 1) * 128;   // i_j or f_j
    const int o1 = o0 + 256;                          // g_j or o_j
    float wA[96], wB[96];
    if (s == 0) {
        #pragma unroll
        for (int k = 0; k < 64; ++k) {
            wA[k] = Wih[mech * 32768 + k * 512 + o0];
            wB[k] = Wih[mech * 32768 + k * 512 + o1];
        }
        #pragma unroll
        for (int k = 0; k < 32; ++k) {
            wA[64 + k] = Whh[mech * 65536 + k * 512 + o0];
            wB[64 + k] = Whh[mech * 65536 + k * 512 + o1];
        }
    } else {
        #pragma unroll
        for (int k = 0; k < 96; ++k) {
            wA[k] = Whh[mech * 65536 + (32 + k) * 512 + o0];
            wB[k] = Whh[mech * 65536 + (32 + k) * 512 + o1];
        }
    }
    const float b0v = (s == 0) ? b_lstm[mech * 512 + o0] : 0.f;
    const float b1v = (s == 0) ? b_lstm[mech * 512 + o1] : 0.f;
    float c_reg = 0.f, cn = 0.f;
    __syncthreads();

    #pragma unroll 1
    for (int t = 0; t < T_LEN; ++t) {
        const int par = t & 1;
        const float* kb = skey + par * 384;
        const float* vb = sval + par * 384;

        // one-wave qc/kc matvec (2 lanes/out over 32 outs)
        auto qk32 = [&](const float* W, const float* hsrc, int var, float* dstL, bool pub) {
            const int out = lane >> 1, s2 = lane & 1, rx = out & 7;
            const float* wrow = W + out * 128;
            const float4* h4 = (const float4*)(hsrc + s2 * 64);
            float p = 0.f;
            #pragma unroll
            for (int j = 0; j < 16; ++j) {
                const float4 w = *(const float4*)(wrow + (((s2 * 16 + j) ^ rx) << 2));
                const float4 hv = h4[j];
                p += w.x * hv.x + w.y * hv.y + w.z * hv.z + w.w * hv.w;
            }
            p += __shfl_xor(p, 1);
            if (s2 == 0) {
                dstL[var * 32 + out] = p;
                if (pub)
                    __hip_atomic_store(&kcg[((par * 5 + mech) * 2 + var) * 32 + out],
                                       p, __ATOMIC_RELAXED, AGT);
            }
        };
        // two-wave vc matvec (1 lane/out over 128 outs, full K)
        auto vc128 = [&](const float* hsrc, int var, int wbase) {
            const int out = (wv - wbase) * 64 + lane, rx = out & 7;
            const float* wrow = swvc + out * 128;
            const float4* h4 = (const float4*)hsrc;
            float p = 0.f;
            #pragma unroll
            for (int c = 0; c < 32; ++c) {
                const float4 w = *(const float4*)(wrow + ((c ^ rx) << 2));
                const float4 hv = h4[c];
                p += w.x * hv.x + w.y * hv.y + w.z * hv.z + w.w * hv.w;
            }
            vcl[var * 128 + out] = p;
            __hip_atomic_store(&vcg[((par * 5 + mech) * 2 + var) * 128 + out],
                               p, __ATOMIC_RELAXED, AGT);
        };

        // ================= S0 =================
        if (wv < 4) {
            const int out = lane, rx = out & 7;
            const float* wrow = swq + out * 128;
            const float4* h4 = (const float4*)(sh + wv * 32);
            float acc = 0.f;
            #pragma unroll
            for (int j = 0; j < 8; ++j) {
                const float4 w = *(const float4*)(wrow + (((wv * 8 + j) ^ rx) << 2));
                const float4 hv = h4[j];
                acc += w.x * hv.x + w.y * hv.y + w.z * hv.z + w.w * hv.w;
            }
            sqp[wv * 64 + out] = acc;
        } else if (wv == 4) {
            qk32(swqc, sh, 0, qcl, false);
        } else if (wv == 5) {
            qk32(swkc, sh, 0, kcl, true);
        } else {
            vc128(sh, 0, 6);
        }
        __syncthreads();   // SYNC1

        // ================= S1 =================
        if (wv == 0) {
            const float q = sqp[lane] + sqp[64 + lane] + sqp[128 + lane] + sqp[192 + lane];
            float l[6];
            #pragma unroll
            for (int k = 0; k < 6; ++k) {
                float p = q * kb[k * 64 + lane];
                p += __shfl_down(p, 32); p += __shfl_down(p, 16); p += __shfl_down(p, 8);
                p += __shfl_down(p, 4);  p += __shfl_down(p, 2);  p += __shfl_down(p, 1);
                l[k] = __shfl(p, 0) * 0.125f;
            }
            const float mx = fmaxf(fmaxf(fmaxf(l[0], l[1]), fmaxf(l[2], l[3])), fmaxf(l[4], l[5]));
            const float e0 = __expf(l[0] - mx), e1 = __expf(l[1] - mx), e2 = __expf(l[2] - mx);
            const float e3 = __expf(l[3] - mx), e4 = __expf(l[4] - mx), e5 = __expf(l[5] - mx);
            const float inv = 1.f / (e0 + e1 + e2 + e3 + e4 + e5);
            sop[lane] = (e0 * vb[lane] + e1 * vb[64 + lane] + e2 * vb[128 + lane]
                       + e3 * vb[192 + lane] + e4 * vb[256 + lane] + e5 * vb[320 + lane]) * inv;
            if (lane == 0) {
                const float nv = e5 * inv;
                snull[mech] = nv;   // local copy in LDS
                __hip_atomic_store(&null_g[par * 8 + mech], nv, __ATOMIC_RELAXED, AGT);
            }
        } else if (wv == 1) {
            const int tn = (t < T_LEN - 1) ? t + 1 : t;
            const float4* kn = (const float4*)(keys + tn * 384);
            float4* kd = (float4*)(skey + ((t + 1) & 1) * 384);
            kd[lane] = kn[lane];
            if (lane < 32) kd[64 + lane] = kn[64 + lane];
        } else if (wv == 2) {
            const int tn = (t < T_LEN - 1) ? t + 1 : t;
            const float4* vn = (const float4*)(vals + tn * 384);
            float4* vd = (float4*)(sval + ((t + 1) & 1) * 384);
            vd[lane] = vn[lane];
            if (lane < 32) vd[64 + lane] = vn[64 + lane];
        }
        __syncthreads();   // SYNC2

        // ================= S2: gates + LSTM =================
        {
            const float4* op = (const float4*)(sop + s * 96);
            float p0 = b0v, p1 = b1v;
            #pragma unroll
            for (int q = 0; q < 24; ++q) {
                const float4 v = op[q];
                p0 += v.x * wA[4 * q] + v.y * wA[4 * q + 1] + v.z * wA[4 * q + 2] + v.w * wA[4 * q + 3];
                p1 += v.x * wB[4 * q] + v.y * wB[4 * q + 1] + v.z * wB[4 * q + 2] + v.w * wB[4 * q + 3];
            }
            const float r0 = p0 + __shfl_xor(p0, 1);
            const float r1 = p1 + __shfl_xor(p1, 1);
            const float t0 = __shfl_xor(r0, 2);
            const float t1 = __shfl_xor(r1, 2);
            const bool even = ((pair & 1) == 0);
            const float gi = even ? r0 : t0;
            const float gg = even ? r1 : t1;
            const float gf = even ? t0 : r0;
            const float go = even ? t1 : r1;
            const float si = 1.f / (1.f + __expf(-gi));
            const float sf = 1.f / (1.f + __expf(-gf));
            const float so = 1.f / (1.f + __expf(-go));
            cn = sf * c_reg + si * tanh_f(gg);
            const float hn = so * tanh_f(cn);
            if ((tid & 3) == 0) shn[tid >> 2] = hn;
        }
        __syncthreads();   // SYNC3

        // ================= S3: variant-1 matvecs =================
        if (wv == 1)      qk32(swqc, shn, 1, qcl, false);
        else if (wv == 2) qk32(swkc, shn, 1, kcl, true);
        else if (wv == 3 || wv == 4) vc128(shn, 1, 3);
        __syncthreads();   // SYNC4 — drains every wave's vmem before s_barrier

        // ================= FLAG rendezvous =================
        {
            const unsigned tgt = (unsigned)(t + 1);
            if (tid == 0)
                __hip_atomic_store(&flags[mech << 6], tgt, __ATOMIC_RELAXED, AGT);
            if (tid < 5 && tid != mech) {
                while (__hip_atomic_load(&flags[tid << 6], __ATOMIC_RELAXED, AGT) < tgt) {}
                snull[tid] = __hip_atomic_load(&null_g[par * 8 + tid], __ATOMIC_RELAXED, AGT);
            }
        }
        __syncthreads();   // SYNC5

        // ================= S5: mask, ctx logits, remote vc =================
        int selfAct;
        {
            const float myn = snull[mech]; int r = 0;
            #pragma unroll
            for (int mm = 0; mm < 5; ++mm) {
                const float o = snull[mm];
                r += (o < myn || (o == myn && mm < mech)) ? 1 : 0;
            }
            selfAct = (r < 3) ? 1 : 0;
        }
        c_reg = selfAct ? cn : c_reg;
        float v0 = 0.f, v1 = 0.f, v2 = 0.f, v3 = 0.f, v4 = 0.f;
        if (wv >= 3 && lane < 32) {
            const int m2 = wv - 3;
            const float nm = snull[m2]; int r2 = 0;
            #pragma unroll
            for (int mm = 0; mm < 5; ++mm) {
                const float o = snull[mm];
                r2 += (o < nm || (o == nm && mm < m2)) ? 1 : 0;
            }
            const int sel2 = (r2 < 3) ? 1 : 0;
            const float kcv = (m2 == mech) ? kcl[sel2 * 32 + lane]
                : __hip_atomic_load(&kcg[((par * 5 + m2) * 2 + sel2) * 32 + lane], __ATOMIC_RELAXED, AGT);
            float p = qcl[selfAct * 32 + lane] * kcv;
            p += __shfl_down(p, 16); p += __shfl_down(p, 8); p += __shfl_down(p, 4);
            p += __shfl_down(p, 2);  p += __shfl_down(p, 1);
            if (lane == 0) slog[m2] = p * 0.17677669529663687f;
        }
        if (tid < 128) {
            int sel[5];
            #pragma unroll
            for (int mm = 0; mm < 5; ++mm) {
                const float nm = snull[mm]; int rr = 0;
                #pragma unroll
                for (int m3 = 0; m3 < 5; ++m3) {
                    const float o = snull[m3];
                    rr += (o < nm || (o == nm && m3 < mm)) ? 1 : 0;
                }
                sel[mm] = (rr < 3) ? 1 : 0;
            }
            v0 = (mech == 0) ? vcl[sel[0] * 128 + tid]
               : __hip_atomic_load(&vcg[((par * 5 + 0) * 2 + sel[0]) * 128 + tid], __ATOMIC_RELAXED, AGT);
            v1 = (mech == 1) ? vcl[sel[1] * 128 + tid]
               : __hip_atomic_load(&vcg[((par * 5 + 1) * 2 + sel[1]) * 128 + tid], __ATOMIC_RELAXED, AGT);
            v2 = (mech == 2) ? vcl[sel[2] * 128 + tid]
               : __hip_atomic_load(&vcg[((par * 5 + 2) * 2 + sel[2]) * 128 + tid], __ATOMIC_RELAXED, AGT);
            v3 = (mech == 3) ? vcl[sel[3] * 128 + tid]
               : __hip_atomic_load(&vcg[((par * 5 + 3) * 2 + sel[3]) * 128 + tid], __ATOMIC_RELAXED, AGT);
            v4 = (mech == 4) ? vcl[sel[4] * 128 + tid]
               : __hip_atomic_load(&vcg[((par * 5 + 4) * 2 + sel[4]) * 128 + tid], __ATOMIC_RELAXED, AGT);
        }
        __syncthreads();   // SYNC6

        // ================= S6: ctx softmax + h2 + store =================
        if (tid < 128) {
            const float l0 = slog[0], l1 = slog[1], l2 = slog[2], l3 = slog[3], l4 = slog[4];
            const float mx = fmaxf(fmaxf(fmaxf(l0, l1), fmaxf(l2, l3)), l4);
            const float e0 = __expf(l0 - mx), e1 = __expf(l1 - mx), e2 = __expf(l2 - mx);
            const float e3 = __expf(l3 - mx), e4 = __expf(l4 - mx);
            const float inv = 1.f / (e0 + e1 + e2 + e3 + e4);
            float hv = selfAct ? shn[tid] : sh[tid];
            if (selfAct) hv += (e0 * v0 + e1 * v1 + e2 * v2 + e3 * v3 + e4 * v4) * inv;
            sh[tid] = hv;
            sop[64 + tid] = hv;
            hidden[t * 640 + mech * 128 + tid] = hv;
        }
        __syncthreads();   // SYNC7
    }
}

// ============ kernel 3: classifier ============
__global__ __launch_bounds__(256) void cls_kernel(
    const float* __restrict__ hidden, const float* __restrict__ Wcls,
    const float* __restrict__ bcls, float* __restrict__ out)
{
    const int t = blockIdx.x * 256 + threadIdx.x;
    if (t >= T_LEN) return;
    float a0 = bcls[0], a1 = bcls[1];
    for (int d = 0; d < 640; ++d) {
        const float h = hidden[t * 640 + d];
        a0 += h * Wcls[d * 2 + 0];
        a1 += h * Wcls[d * 2 + 1];
    }
    out[t * 2 + 0] = a0;
    out[t * 2 + 1] = a1;
}

extern "C" void kernel_launch(void* const* d_in, const int* in_sizes, int n_in,
                              void* d_out, int out_size, void* d_ws, size_t ws_size,
                              hipStream_t stream)
{
    (void)in_sizes; (void)n_in; (void)out_size; (void)ws_size;
    const float* bert  = (const float*)d_in[0];
    const int*   uidx  = (const int*)d_in[1];
    const int*   pidx  = (const int*)d_in[2];
    const float* disg  = (const float*)d_in[3];
    const float* udisg = (const float*)d_in[4];
    const float* utab  = (const float*)d_in[5];
    const float* ptab  = (const float*)d_in[6];
    const float* Wk0 = (const float*)d_in[7],  *Wv0 = (const float*)d_in[8];
    const float* Wk1 = (const float*)d_in[9],  *Wv1 = (const float*)d_in[10];
    const float* Wk2 = (const float*)d_in[11], *Wv2 = (const float*)d_in[12];
    const float* Wk3 = (const float*)d_in[13], *Wv3 = (const float*)d_in[14];
    const float* Wk4 = (const float*)d_in[15], *Wv4 = (const float*)d_in[16];
    const float* Wq   = (const float*)d_in[17];
    const float* Wih  = (const float*)d_in[18];
    const float* Whh  = (const float*)d_in[19];
    const float* bl   = (const float*)d_in[20];
    const float* Wqc  = (const float*)d_in[21];
    const float* Wkc  = (const float*)d_in[22];
    const float* Wvc  = (const float*)d_in[23];
    const float* Wcls = (const float*)d_in[24];
    const float* bcls = (const float*)d_in[25];

    char* ws = (char*)d_ws;
    unsigned* flags = (unsigned*)(ws + 0x100);   // stride 64 uints = 256 B
    float* null_g  = (float*)(ws + 0x600);
    float* kcg     = (float*)(ws + 0x700);
    float* vcg     = (float*)(ws + 0x1200);
    float* keys    = (float*)(ws + 0x4000);
    float* vals    = (float*)(ws + 0x4000 + 786432);
    float* hidden  = (float*)(ws + 0x4000 + 2 * 786432);

    hipMemsetAsync(d_ws, 0, 0x600, stream);   // zero the flag lines

    hipLaunchKernelGGL(precompute_kv, dim3(T_LEN), dim3(128), 0, stream,
        bert, uidx, pidx, disg, udisg, utab, ptab,
        Wk0, Wv0, Wk1, Wv1, Wk2, Wv2, Wk3, Wv3, Wk4, Wv4, keys, vals);

    const int smem_bytes = SMEM_FLOATS * 4;   // 141632 B < 160 KiB
    (void)hipFuncSetAttribute((const void*)rim_scan,
                              hipFuncAttributeMaxDynamicSharedMemorySize, smem_bytes);
    hipLaunchKernelGGL(rim_scan, dim3(33), dim3(512), smem_bytes, stream,
        Wq, Wih, Whh, bl, Wqc, Wkc, Wvc, keys, vals, hidden, flags, null_g, kcg, vcg);

    hipLaunchKernelGGL(cls_kernel, dim3(2), dim3(256), 0, stream,
        hidden, Wcls, bcls, (float*)d_out);
}